// Round 5
// baseline (32.123 us; speedup 1.0000x reference)
//
#include <hip/hip_runtime.h>
#include <math.h>

#define BS   64
#define NW   8
#define NK   10
#define NP   16
#define NT   20
#define NN   4096
#define NTH  512
#define NWAVES (NTH / 64)
#define EPT  (NN / NTH)               // 8 negatives per thread, register-resident
#define NBINS 4096                    // single 12-bit radix pass
#define HISTPAD (NBINS + NBINS / 8)   // 4608: bin i stored at i + (i>>3)  (stride-9, bank-conflict-free rank)
#define CANDMAX 2048
#define SEGCAP 512                    // per-wave selected-segment capacity (a wave owns only 512 elems)
#define LOG2PI 1.8378770664093453f
#define LOG2E  1.4426950408889634f
#define LN2    0.6931471805599453f

__device__ __constant__ int d_wpix[NW] = {0, 2, 4, 6, 9, 12, 15, 19};

__device__ __forceinline__ unsigned int lanes_below(unsigned long long m) {
    unsigned int lt = __builtin_amdgcn_mbcnt_lo((unsigned int)m, 0u);
    return __builtin_amdgcn_mbcnt_hi((unsigned int)(m >> 32), lt);
}

__global__ __launch_bounds__(NTH, 4) void mdn_row_kernel(
    const float* __restrict__ mu,
    const float* __restrict__ sigma,
    const float* __restrict__ pi,
    const float* __restrict__ neg,
    const float* __restrict__ pos,
    const int* __restrict__ p_wh,
    const int* __restrict__ p_cap,
    float* __restrict__ rowres,
    unsigned int* __restrict__ cnt,
    float* __restrict__ out)
{
    __shared__ unsigned int s_hist[HISTPAD];     // 18KB padded histogram
    __shared__ unsigned int s_cand[CANDMAX];     // 8KB boundary-bucket candidates
    __shared__ float s_seg[3 * NWAVES * SEGCAP]; // 48KB: segx | segy | sege, wave w owns [w*512, w*512+512)
    __shared__ float s_posx[NP], s_posy[NP];
    __shared__ float s_mu0[NK], s_mu1[NK], s_is0[NK], s_is1[NK], s_ck2[NK];
    __shared__ unsigned int s_wsum[NWAVES];
    __shared__ float s_red[2 * NWAVES];
    __shared__ unsigned int s_bucket, s_below, s_candcnt, s_P;
    __shared__ float s_dmin;

    const int row  = blockIdx.x;      // 0 .. BS*NW-1
    const int b    = row / NW;
    const int w    = row % NW;
    const int tid  = threadIdx.x;
    const int lane = tid & 63;
    const int wid  = tid >> 6;

    // ---------- issue global loads FIRST (latency hides under phase 0) ----------
    const float2* negp = (const float2*)(neg + (size_t)b * NN * 2);
    float2 nv[EPT];
    #pragma unroll
    for (int c = 0; c < EPT; ++c) nv[c] = negp[c * NTH + tid];

    // ---------- phase 0: zero hist, stage positives, mixture constants ----------
    if (tid < NP) {
        const float* pp = pos + (((size_t)b * NP + tid) * NT + d_wpix[w]) * 2;
        s_posx[tid] = pp[0];
        s_posy[tid] = pp[1];
    }
    if (tid >= 64 && tid < 64 + NK) {          // wave 1: per-component precompute
        const int k = tid - 64;
        const float* pib = pi    + ((size_t)b * NW + w) * NK;
        const float* mub = mu    + ((size_t)b * NW + w) * NK * 2;
        const float* sgb = sigma + ((size_t)b * NW + w) * NK * 2;
        float m = pib[0];
        for (int j = 1; j < NK; ++j) m = fmaxf(m, pib[j]);
        float se = 0.f;
        for (int j = 0; j < NK; ++j) se += __expf(pib[j] - m);
        float lse = m + __logf(se);
        float s0 = sgb[2 * k], s1 = sgb[2 * k + 1];
        s_mu0[k] = mub[2 * k];
        s_mu1[k] = mub[2 * k + 1];
        s_is0[k] = 1.0f / s0;
        s_is1[k] = 1.0f / s1;
        s_ck2[k] = ((pib[k] - lse) - __logf(s0) - __logf(s1) - LOG2PI) * LOG2E;
    }
    for (int i = tid; i < HISTPAD; i += NTH) s_hist[i] = 0;
    if (tid == 32) s_candcnt = 0;
    __syncthreads();                                           // B1

    float px[NP], py[NP];
    #pragma unroll
    for (int p = 0; p < NP; ++p) { px[p] = s_posx[p]; py[p] = s_posy[p]; }

    // ---------- phase 1: distances (registers) + padded histogram ----------
    float nx[EPT], ny[EPT];
    unsigned int ub[EPT];
    float lmin = INFINITY;
    #pragma unroll
    for (int c = 0; c < EPT; ++c) {
        nx[c] = nv[c].x; ny[c] = nv[c].y;
        float best0 = INFINITY, best1 = INFINITY;   // pairwise tree halves dep chain
        #pragma unroll
        for (int p = 0; p < NP; p += 2) {
            float dx0 = px[p] - nx[c],     dy0 = py[p] - ny[c];
            float dx1 = px[p + 1] - nx[c], dy1 = py[p + 1] - ny[c];
            best0 = fminf(best0, fmaf(dx0, dx0, dy0 * dy0));
            best1 = fminf(best1, fmaf(dx1, dx1, dy1 * dy1));
        }
        float dd = sqrtf(fminf(best0, best1));       // sqrt(min) == min(sqrt)
        ub[c] = __float_as_uint(dd);
        lmin = fminf(lmin, dd);
        unsigned int h = ub[c] >> 20;
        atomicAdd(&s_hist[h + (h >> 3)], 1u);
    }
    #pragma unroll
    for (int off = 32; off; off >>= 1) lmin = fminf(lmin, __shfl_down(lmin, off, 64));
    if (lane == 0) s_red[wid] = lmin;
    __syncthreads();                                           // B2
    if (tid == 0) {
        float m = s_red[0];
        for (int i = 1; i < NWAVES; ++i) m = fminf(m, s_red[i]);
        s_dmin = m;
    }

    const int cap = *p_cap;
    const bool do_sel = (cap > 0 && cap < NN);
    const int wh = *p_wh;

    unsigned int selmask = 0xFFu;

    if (do_sel) {
        // ---------- phase 2: rank over 4096 bins (stride-9 padded, conflict-free) ----------
        const int rbase = tid * 9;                 // padded addr of bin 8*tid
        unsigned int hv[8];
        unsigned int cnt8 = 0;
        #pragma unroll
        for (int j = 0; j < 8; ++j) { hv[j] = s_hist[rbase + j]; cnt8 += hv[j]; }
        unsigned int v = cnt8;
        #pragma unroll
        for (int off = 1; off < 64; off <<= 1) {
            unsigned int o = __shfl_up(v, off, 64);
            if (lane >= off) v += o;
        }
        if (lane == 63) s_wsum[wid] = v;
        __syncthreads();                                       // B3
        unsigned int wbase = 0;
        for (int i = 0; i < wid; ++i) wbase += s_wsum[i];
        const unsigned int incl = v + wbase;
        const unsigned int excl = incl - cnt8;
        const unsigned int capu = (unsigned int)cap;
        if (excl < capu && capu <= incl) {
            unsigned int run = excl;
            #pragma unroll
            for (int j = 0; j < 8; ++j) {
                unsigned int c2 = hv[j];
                if (capu <= run + c2) { s_bucket = (unsigned int)(tid * 8 + j); s_below = run; break; }
                run += c2;
            }
        }
        __syncthreads();                                       // B4
        const unsigned int B = s_bucket;

        // ---------- phase 3: ballot-aggregated candidate compaction ----------
        #pragma unroll
        for (int c = 0; c < EPT; ++c) {
            bool isc = ((ub[c] >> 20) == B);
            unsigned long long m = __ballot(isc);
            if (m) {
                int leader = __builtin_ctzll(m);
                unsigned int base2 = 0;
                if (lane == leader) base2 = atomicAdd(&s_candcnt, (unsigned int)__popcll(m));
                base2 = __shfl(base2, leader, 64);
                if (isc) {
                    unsigned int p0 = base2 + lanes_below(m);
                    if (p0 < CANDMAX)
                        s_cand[p0] = (ub[c] << 12) | (unsigned int)(c * NTH + tid);
                }
            }
        }
        __syncthreads();                                       // B5

        // ---------- phase 4: exact rank among candidates (packed keys distinct) ----------
        const int C = (int)min(s_candcnt, (unsigned int)CANDMAX);
        const int remT = cap - (int)s_below;    // how many to take from bucket B
        for (int i = tid; i < C; i += NTH) {
            unsigned int pv = s_cand[i];
            int less = 0;
            for (int j = 0; j < C; ++j) less += (s_cand[j] < pv) ? 1 : 0;
            if (less == remT - 1) s_P = pv;     // the remT-th smallest packed key
        }
        __syncthreads();                                       // B6
        const unsigned int P = s_P;

        selmask = 0;
        #pragma unroll
        for (int c = 0; c < EPT; ++c) {
            const unsigned int u = ub[c];
            const unsigned int top = u >> 20;
            bool s = (top < B) ||
                     (top == B && (((u << 12) | (unsigned int)(c * NTH + tid)) <= P));
            selmask |= (s ? 1u : 0u) << c;
        }
    } else {
        __syncthreads();                 // make s_dmin visible (uniform branch)
    }

    // ---------- phase 5: per-wave ballot compaction into private LDS segment ----------
    float* segx = s_seg;
    float* segy = s_seg + NWAVES * SEGCAP;
    float* sege = s_seg + 2 * NWAVES * SEGCAP;
    const int segbase = wid << 9;
    const float dmin = s_dmin;
    int wcnt = 0;
    #pragma unroll
    for (int c = 0; c < EPT; ++c) {
        bool s = (selmask >> c) & 1u;
        unsigned long long m = __ballot(s);
        if (s) {
            int p0 = segbase + wcnt + (int)lanes_below(m);
            float dd = __uint_as_float(ub[c]);
            segx[p0] = wh ? ny[c] : nx[c];
            segy[p0] = wh ? nx[c] : ny[c];
            sege[p0] = exp2f((dmin - dd) * LOG2E);   // softmax numerator
        }
        wcnt += (int)__popcll(m);
    }
    asm volatile("s_waitcnt lgkmcnt(0)" ::: "memory");  // wave-local LDS RAW: no barrier needed

    // ---------- phase 6: each wave consumes its own dense segment ----------
    float c_mu0[NK], c_mu1[NK], c_is0[NK], c_is1[NK], c_ck2[NK];
    #pragma unroll
    for (int k = 0; k < NK; ++k) {
        c_mu0[k] = s_mu0[k]; c_mu1[k] = s_mu1[k];
        c_is0[k] = s_is0[k]; c_is1[k] = s_is1[k];
        c_ck2[k] = s_ck2[k];
    }
    float accZ = 0.f, accS = 0.f;
    for (int i = lane; i < wcnt; i += 64) {
        const float x0 = segx[segbase + i];
        const float x1 = segy[segbase + i];
        const float e  = sege[segbase + i];
        float a[NK];
        #pragma unroll
        for (int k = 0; k < NK; ++k) {
            float z0 = (x0 - c_mu0[k]) * c_is0[k];
            float z1 = (x1 - c_mu1[k]) * c_is1[k];
            float q  = fmaf(z0, z0, z1 * z1);
            a[k] = fmaf(q, -0.5f * LOG2E, c_ck2[k]);
        }
        // max tree (depth 4)
        float t0 = fmaxf(a[0], a[1]), t1 = fmaxf(a[2], a[3]);
        float t2 = fmaxf(a[4], a[5]), t3 = fmaxf(a[6], a[7]);
        float t4 = fmaxf(a[8], a[9]);
        float m2 = fmaxf(fmaxf(fmaxf(t0, t1), fmaxf(t2, t3)), t4);
        float se = 0.f;
        #pragma unroll
        for (int k = 0; k < NK; ++k) se += exp2f(a[k] - m2);
        float lp = LN2 * (m2 + log2f(se));
        accZ += e;
        accS += e * lp;
    }

    // ---------- block reduction + fused deterministic fan-in finalize ----------
    #pragma unroll
    for (int off = 32; off; off >>= 1) {
        accZ += __shfl_down(accZ, off, 64);
        accS += __shfl_down(accS, off, 64);
    }
    if (lane == 0) { s_red[wid] = accZ; s_red[NWAVES + wid] = accS; }
    __syncthreads();                                           // B7
    if (tid == 0) {
        float Z = 0.f, S = 0.f;
        for (int i = 0; i < NWAVES; ++i) { Z += s_red[i]; S += s_red[NWAVES + i]; }
        rowres[row] = S / Z;
        __threadfence();                       // release rowres
        unsigned int old = atomicAdd(&cnt[b], 1u);
        if (old == NW - 1) {                   // last of the 8 waypoint blocks
            __threadfence();                   // acquire others' rowres
            float s = 0.f;
            #pragma unroll
            for (int j = 0; j < NW; ++j) s += rowres[b * NW + j];
            out[b] = -s * (1.0f / NW);         // fixed-order sum: deterministic
        }
    }
}

extern "C" void kernel_launch(void* const* d_in, const int* in_sizes, int n_in,
                              void* d_out, int out_size, void* d_ws, size_t ws_size,
                              hipStream_t stream)
{
    const float* mu    = (const float*)d_in[0];
    const float* sigma = (const float*)d_in[1];
    const float* pi    = (const float*)d_in[2];
    const float* neg   = (const float*)d_in[3];
    const float* pos   = (const float*)d_in[4];
    const int*   wh    = (const int*)d_in[5];
    const int*   cap   = (const int*)d_in[6];
    float* rowres = (float*)d_ws;                              // 512 floats
    unsigned int* cnt = (unsigned int*)((char*)d_ws + 2048);   // 64 uints
    float* out    = (float*)d_out;

    hipMemsetAsync(cnt, 0, BS * sizeof(unsigned int), stream); // fan-in counters must start at 0
    mdn_row_kernel<<<BS * NW, NTH, 0, stream>>>(mu, sigma, pi, neg, pos, wh, cap, rowres, cnt, out);
}

// Round 7
// 29.638 us; speedup vs baseline: 1.0838x; 1.0838x over previous
//
#include <hip/hip_runtime.h>
#include <math.h>

#define BS   64
#define NW   8
#define NK   10
#define NP   16
#define NT   20
#define NN   4096
#define NTH  512
#define NWAVES (NTH / 64)
#define EPT  (NN / NTH)               // 8 negatives per thread, register-resident
#define NBINS 4096                    // single 12-bit radix pass
#define HISTPAD (NBINS + NBINS / 8)   // bin i at i+(i>>3); rank read stride-9 = conflict-free
#define CANDMAX 2048
#define LOG2PI 1.8378770664093453f
#define LOG2E  1.4426950408889634f
#define LN2    0.6931471805599453f

__device__ __constant__ int d_wpix[NW] = {0, 2, 4, 6, 9, 12, 15, 19};

__device__ __forceinline__ unsigned int lanes_below(unsigned long long m) {
    unsigned int lt = __builtin_amdgcn_mbcnt_lo((unsigned int)m, 0u);
    return __builtin_amdgcn_mbcnt_hi((unsigned int)(m >> 32), lt);
}

__global__ __launch_bounds__(NTH, 4) void mdn_row_kernel(
    const float* __restrict__ mu,
    const float* __restrict__ sigma,
    const float* __restrict__ pi,
    const float* __restrict__ neg,
    const float* __restrict__ pos,
    const int* __restrict__ p_wh,
    const int* __restrict__ p_cap,
    float* __restrict__ rowres)
{
    __shared__ unsigned int s_hist[HISTPAD];     // 18KB padded histogram
    __shared__ unsigned int s_cand[CANDMAX];     // 8KB boundary-bucket candidates
    __shared__ float s_posx[NP], s_posy[NP];
    __shared__ float s_mu0[NK], s_mu1[NK], s_is0[NK], s_is1[NK], s_ck2[NK];
    __shared__ unsigned int s_wsum[NWAVES];
    __shared__ float s_red[2 * NWAVES];
    __shared__ unsigned int s_bucket, s_below, s_candcnt, s_P;

    const int row  = blockIdx.x;      // 0 .. BS*NW-1
    const int b    = row / NW;
    const int w    = row % NW;
    const int tid  = threadIdx.x;
    const int lane = tid & 63;
    const int wid  = tid >> 6;

    // ---------- issue the negative loads first (latency hides under phase 0) ----------
    const float2* negp = (const float2*)(neg + (size_t)b * NN * 2);
    float2 nv[EPT];
    #pragma unroll
    for (int c = 0; c < EPT; ++c) nv[c] = negp[c * NTH + tid];

    // ---------- phase 0: zero hist, stage positives, mixture constants ----------
    for (int i = tid; i < HISTPAD; i += NTH) s_hist[i] = 0;
    if (tid < NP) {
        const float* pp = pos + (((size_t)b * NP + tid) * NT + d_wpix[w]) * 2;
        s_posx[tid] = pp[0];
        s_posy[tid] = pp[1];
    }
    if (tid >= 64 && tid < 64 + NK) {          // wave 1: per-component precompute
        const int k = tid - 64;
        const float* pib = pi    + ((size_t)b * NW + w) * NK;
        const float* mub = mu    + ((size_t)b * NW + w) * NK * 2;
        const float* sgb = sigma + ((size_t)b * NW + w) * NK * 2;
        float m = pib[0];
        for (int j = 1; j < NK; ++j) m = fmaxf(m, pib[j]);
        float se = 0.f;
        for (int j = 0; j < NK; ++j) se += __expf(pib[j] - m);
        float lse = m + __logf(se);
        float s0 = sgb[2 * k], s1 = sgb[2 * k + 1];
        s_mu0[k] = mub[2 * k];
        s_mu1[k] = mub[2 * k + 1];
        s_is0[k] = 1.0f / s0;
        s_is1[k] = 1.0f / s1;
        s_ck2[k] = ((pib[k] - lse) - __logf(s0) - __logf(s1) - LOG2PI) * LOG2E;
    }
    if (tid == 32) s_candcnt = 0;
    __syncthreads();                                           // B1

    const int cap = *p_cap;
    const bool do_sel = (cap > 0 && cap < NN);
    const int wh = *p_wh;

    // ---------- loop A: distances + padded histogram ----------
    float px[NP], py[NP];
    #pragma unroll
    for (int p = 0; p < NP; ++p) { px[p] = s_posx[p]; py[p] = s_posy[p]; }
    unsigned int ub[EPT];
    #pragma unroll
    for (int c = 0; c < EPT; ++c) {
        float vx = nv[c].x, vy = nv[c].y;
        float best0 = INFINITY, best1 = INFINITY;   // pairwise tree halves dep chain
        #pragma unroll
        for (int p = 0; p < NP; p += 2) {
            float dx0 = px[p] - vx,     dy0 = py[p] - vy;
            float dx1 = px[p + 1] - vx, dy1 = py[p + 1] - vy;
            best0 = fminf(best0, fmaf(dx0, dx0, dy0 * dy0));
            best1 = fminf(best1, fmaf(dx1, dx1, dy1 * dy1));
        }
        float dd = sqrtf(fminf(best0, best1));      // sqrt(min) == min(sqrt)
        ub[c] = __float_as_uint(dd);
        unsigned int h = ub[c] >> 20;
        atomicAdd(&s_hist[h + (h >> 3)], 1u);
    }

    // ---------- loop B: mixture log-prob + softmax numerator for ALL owned elems ----------
    // e = exp(dmin - d) everywhere would be exp(dmin)*exp(-d); exp(dmin) cancels
    // in S/Z, so no stabilization / dmin reduction is needed (d ∈ [0, ~6]).
    float c_mu0[NK], c_mu1[NK], c_is0[NK], c_is1[NK], c_ck2[NK];
    #pragma unroll
    for (int k = 0; k < NK; ++k) {
        c_mu0[k] = s_mu0[k]; c_mu1[k] = s_mu1[k];
        c_is0[k] = s_is0[k]; c_is1[k] = s_is1[k];
        c_ck2[k] = s_ck2[k];
    }
    float eN[EPT], lp[EPT];
    #pragma unroll
    for (int c = 0; c < EPT; ++c) {
        const float x0 = wh ? nv[c].y : nv[c].x;    // reversal matters vs mu/sigma
        const float x1 = wh ? nv[c].x : nv[c].y;
        float a[NK];
        #pragma unroll
        for (int k = 0; k < NK; ++k) {
            float z0 = (x0 - c_mu0[k]) * c_is0[k];
            float z1 = (x1 - c_mu1[k]) * c_is1[k];
            float q  = fmaf(z0, z0, z1 * z1);
            a[k] = fmaf(q, -0.5f * LOG2E, c_ck2[k]);
        }
        float t0 = fmaxf(a[0], a[1]), t1 = fmaxf(a[2], a[3]);
        float t2 = fmaxf(a[4], a[5]), t3 = fmaxf(a[6], a[7]);
        float m2 = fmaxf(fmaxf(fmaxf(t0, t1), fmaxf(t2, t3)), fmaxf(a[8], a[9]));
        float se = 0.f;
        #pragma unroll
        for (int k = 0; k < NK; ++k) se += exp2f(a[k] - m2);
        lp[c] = LN2 * (m2 + log2f(se));
        eN[c] = exp2f(-__uint_as_float(ub[c]) * LOG2E);
    }
    __syncthreads();                                           // B2 (hist complete)

    unsigned int selmask = 0xFFu;
    if (do_sel) {
        // ---------- rank over 4096 bins (stride-9 padded, conflict-free) ----------
        const int rbase = tid * 9;                 // padded addr of bin 8*tid
        unsigned int hv[8];
        unsigned int cnt8 = 0;
        #pragma unroll
        for (int j = 0; j < 8; ++j) { hv[j] = s_hist[rbase + j]; cnt8 += hv[j]; }
        unsigned int v = cnt8;
        #pragma unroll
        for (int off = 1; off < 64; off <<= 1) {
            unsigned int o = __shfl_up(v, off, 64);
            if (lane >= off) v += o;
        }
        if (lane == 63) s_wsum[wid] = v;
        __syncthreads();                                       // B3
        unsigned int wbase = 0;
        for (int i = 0; i < wid; ++i) wbase += s_wsum[i];
        const unsigned int incl = v + wbase;
        const unsigned int excl = incl - cnt8;
        const unsigned int capu = (unsigned int)cap;
        if (excl < capu && capu <= incl) {
            unsigned int run = excl;
            #pragma unroll
            for (int j = 0; j < 8; ++j) {
                unsigned int c2 = hv[j];
                if (capu <= run + c2) { s_bucket = (unsigned int)(tid * 8 + j); s_below = run; break; }
                run += c2;
            }
        }
        __syncthreads();                                       // B4
        const unsigned int B = s_bucket;

        // ---------- ballot-aggregated candidate compaction ----------
        #pragma unroll
        for (int c = 0; c < EPT; ++c) {
            bool isc = ((ub[c] >> 20) == B);
            unsigned long long m = __ballot(isc);
            if (m) {
                int leader = __builtin_ctzll(m);
                unsigned int base2 = 0;
                if (lane == leader) base2 = atomicAdd(&s_candcnt, (unsigned int)__popcll(m));
                base2 = __shfl(base2, leader, 64);
                if (isc) {
                    unsigned int p0 = base2 + lanes_below(m);
                    if (p0 < CANDMAX)
                        s_cand[p0] = (ub[c] << 12) | (unsigned int)(c * NTH + tid);
                }
            }
        }
        __syncthreads();                                       // B5

        // ---------- exact rank among candidates (packed keys distinct) ----------
        const int C = (int)min(s_candcnt, (unsigned int)CANDMAX);
        const int remT = cap - (int)s_below;    // how many to take from bucket B
        for (int i = tid; i < C; i += NTH) {
            unsigned int pv = s_cand[i];
            int less = 0;
            for (int j = 0; j < C; ++j) less += (s_cand[j] < pv) ? 1 : 0;
            if (less == remT - 1) s_P = pv;     // the remT-th smallest packed key
        }
        __syncthreads();                                       // B6
        const unsigned int P = s_P;

        selmask = 0;
        #pragma unroll
        for (int c = 0; c < EPT; ++c) {
            const unsigned int u = ub[c];
            const unsigned int top = u >> 20;
            bool s = (top < B) ||
                     (top == B && (((u << 12) | (unsigned int)(c * NTH + tid)) <= P));
            selmask |= (s ? 1u : 0u) << c;
        }
    }

    // ---------- register masked accumulate (no compaction, no LDS round trip) ----------
    float accZ = 0.f, accS = 0.f;
    #pragma unroll
    for (int c = 0; c < EPT; ++c) {
        if ((selmask >> c) & 1u) {
            accZ += eN[c];
            accS += eN[c] * lp[c];
        }
    }

    // ---------- block reduction ----------
    #pragma unroll
    for (int off = 32; off; off >>= 1) {
        accZ += __shfl_down(accZ, off, 64);
        accS += __shfl_down(accS, off, 64);
    }
    if (lane == 0) { s_red[wid] = accZ; s_red[NWAVES + wid] = accS; }
    __syncthreads();                                           // B7
    if (tid == 0) {
        float Z = 0.f, S = 0.f;
        for (int i = 0; i < NWAVES; ++i) { Z += s_red[i]; S += s_red[NWAVES + i]; }
        rowres[row] = S / Z;
    }
}

__global__ void mdn_finalize_kernel(const float* __restrict__ rowres,
                                    float* __restrict__ out)
{
    int b = threadIdx.x;
    if (b < BS) {
        float s = 0.f;
        #pragma unroll
        for (int w = 0; w < NW; ++w) s += rowres[b * NW + w];
        out[b] = -s * (1.0f / NW);
    }
}

extern "C" void kernel_launch(void* const* d_in, const int* in_sizes, int n_in,
                              void* d_out, int out_size, void* d_ws, size_t ws_size,
                              hipStream_t stream)
{
    const float* mu    = (const float*)d_in[0];
    const float* sigma = (const float*)d_in[1];
    const float* pi    = (const float*)d_in[2];
    const float* neg   = (const float*)d_in[3];
    const float* pos   = (const float*)d_in[4];
    const int*   wh    = (const int*)d_in[5];
    const int*   cap   = (const int*)d_in[6];
    float* rowres = (float*)d_ws;   // BS*NW floats scratch
    float* out    = (float*)d_out;

    mdn_row_kernel<<<BS * NW, NTH, 0, stream>>>(mu, sigma, pi, neg, pos, wh, cap, rowres);
    mdn_finalize_kernel<<<1, 64, 0, stream>>>(rowres, out);
}

// Round 8
// 26.849 us; speedup vs baseline: 1.1964x; 1.1039x over previous
//
#include <hip/hip_runtime.h>
#include <math.h>

#define BS   64
#define NW   8
#define NK   10
#define NP   16
#define NT   20
#define NN   4096
#define NTH  512
#define NWAVES (NTH / 64)
#define EPT  (NN / NTH)               // 8 negatives per thread, register-resident
#define NB1  512                      // pass-1 bins: top 9 bits (sign+exponent) of dist bits
#define NB2  4096                     // pass-2 bins: mantissa bits [22:11]
#define H2PAD(i) ((i) + ((i) >> 3))   // stride-9 padding for pass-2 hist (conflict-free rank read)
#define NB2PAD (NB2 + NB2 / 8)
#define CAND2MAX 256
#define LOG2PI 1.8378770664093453f
#define LOG2E  1.4426950408889634f
#define LN2    0.6931471805599453f

__device__ __constant__ int d_wpix[NW] = {0, 2, 4, 6, 9, 12, 15, 19};

__device__ __forceinline__ unsigned int lanes_below(unsigned long long m) {
    unsigned int lt = __builtin_amdgcn_mbcnt_lo((unsigned int)m, 0u);
    return __builtin_amdgcn_mbcnt_hi((unsigned int)(m >> 32), lt);
}

__global__ __launch_bounds__(NTH, 4) void mdn_row_kernel(
    const float* __restrict__ mu,
    const float* __restrict__ sigma,
    const float* __restrict__ pi,
    const float* __restrict__ neg,
    const float* __restrict__ pos,
    const int* __restrict__ p_wh,
    const int* __restrict__ p_cap,
    float* __restrict__ rowres)
{
    __shared__ unsigned int s_h1[NWAVES * NB1];  // 16KB per-wave privatized exponent hist
    __shared__ unsigned int s_h2[NB2PAD];        // 18KB padded mantissa hist
    __shared__ unsigned int s_cand2[CAND2MAX];   // 1KB exact-tie candidates
    __shared__ float s_posx[NP], s_posy[NP];
    __shared__ float s_mu0[NK], s_mu1[NK], s_is0[NK], s_is1[NK], s_ck2[NK];
    __shared__ unsigned int s_wsum[NWAVES];
    __shared__ float s_red[2 * NWAVES];
    __shared__ unsigned int s_binE, s_belowE, s_binM, s_belowM, s_c2cnt, s_P;

    const int row  = blockIdx.x;      // 0 .. BS*NW-1
    const int b    = row / NW;
    const int w    = row % NW;
    const int tid  = threadIdx.x;
    const int lane = tid & 63;
    const int wid  = tid >> 6;

    // ---------- phase 0: zero hists, stage positives, mixture constants ----------
    #pragma unroll
    for (int j = 0; j < (NWAVES * NB1) / NTH; ++j) s_h1[tid + j * NTH] = 0;
    for (int i = tid; i < NB2PAD; i += NTH) s_h2[i] = 0;
    if (tid < NP) {
        const float* pp = pos + (((size_t)b * NP + tid) * NT + d_wpix[w]) * 2;
        s_posx[tid] = pp[0];
        s_posy[tid] = pp[1];
    }
    if (tid >= 64 && tid < 64 + NK) {          // wave 1: per-component precompute
        const int k = tid - 64;
        const float* pib = pi    + ((size_t)b * NW + w) * NK;
        const float* mub = mu    + ((size_t)b * NW + w) * NK * 2;
        const float* sgb = sigma + ((size_t)b * NW + w) * NK * 2;
        float m = pib[0];
        for (int j = 1; j < NK; ++j) m = fmaxf(m, pib[j]);
        float se = 0.f;
        for (int j = 0; j < NK; ++j) se += __expf(pib[j] - m);
        float lse = m + __logf(se);
        float s0 = sgb[2 * k], s1 = sgb[2 * k + 1];
        s_mu0[k] = mub[2 * k];
        s_mu1[k] = mub[2 * k + 1];
        s_is0[k] = 1.0f / s0;
        s_is1[k] = 1.0f / s1;
        s_ck2[k] = ((pib[k] - lse) - __logf(s0) - __logf(s1) - LOG2PI) * LOG2E;
    }
    if (tid == 32) s_c2cnt = 0;
    __syncthreads();                                           // B1

    const int cap = *p_cap;
    const bool do_sel = (cap > 0 && cap < NN);
    const int wh = *p_wh;

    // ---------- loop A: distances + per-wave privatized exponent histogram ----------
    float px[NP], py[NP];
    #pragma unroll
    for (int p = 0; p < NP; ++p) { px[p] = s_posx[p]; py[p] = s_posy[p]; }
    const float2* negp = (const float2*)(neg + (size_t)b * NN * 2);
    float2 nv[EPT];
    unsigned int ub[EPT];
    #pragma unroll
    for (int c = 0; c < EPT; ++c) {
        float2 v = negp[c * NTH + tid];
        nv[c] = v;
        float best0 = INFINITY, best1 = INFINITY;   // pairwise tree halves dep chain
        #pragma unroll
        for (int p = 0; p < NP; p += 2) {
            float dx0 = px[p] - v.x,     dy0 = py[p] - v.y;
            float dx1 = px[p + 1] - v.x, dy1 = py[p + 1] - v.y;
            best0 = fminf(best0, fmaf(dx0, dx0, dy0 * dy0));
            best1 = fminf(best1, fmaf(dx1, dx1, dy1 * dy1));
        }
        float dd = sqrtf(fminf(best0, best1));      // select on sqrt bits: matches ref ties
        ub[c] = __float_as_uint(dd);
        atomicAdd(&s_h1[wid * NB1 + (ub[c] >> 23)], 1u);
    }

    // ---------- loop B: mixture log-prob + softmax numerator for ALL owned elems ----------
    // exp(dmin) cancels in S/Z -> no stabilization / dmin reduction needed.
    // Mixture constants stay in LDS (broadcast reads) to keep VGPRs low.
    float eN[EPT], lp[EPT];
    #pragma unroll
    for (int c = 0; c < EPT; ++c) {
        const float x0 = wh ? nv[c].y : nv[c].x;    // reversal matters vs mu/sigma
        const float x1 = wh ? nv[c].x : nv[c].y;
        float a[NK];
        #pragma unroll
        for (int k = 0; k < NK; ++k) {
            float z0 = (x0 - s_mu0[k]) * s_is0[k];
            float z1 = (x1 - s_mu1[k]) * s_is1[k];
            float q  = fmaf(z0, z0, z1 * z1);
            a[k] = fmaf(q, -0.5f * LOG2E, s_ck2[k]);
        }
        float t0 = fmaxf(a[0], a[1]), t1 = fmaxf(a[2], a[3]);
        float t2 = fmaxf(a[4], a[5]), t3 = fmaxf(a[6], a[7]);
        float m2 = fmaxf(fmaxf(fmaxf(t0, t1), fmaxf(t2, t3)), fmaxf(a[8], a[9]));
        float se = 0.f;
        #pragma unroll
        for (int k = 0; k < NK; ++k) se += exp2f(a[k] - m2);
        lp[c] = LN2 * (m2 + log2f(se));
        eN[c] = exp2f(-__uint_as_float(ub[c]) * LOG2E);
    }
    __syncthreads();                                           // B2 (hist1 complete)

    unsigned int selmask = 0xFFu;
    if (do_sel) {
        const unsigned int capu = (unsigned int)cap;

        // ---------- rank 1: 512 exponent bins, one bin per thread ----------
        unsigned int cnt1 = 0;
        #pragma unroll
        for (int q = 0; q < NWAVES; ++q) cnt1 += s_h1[q * NB1 + tid];
        {
            unsigned int v = cnt1;
            #pragma unroll
            for (int off = 1; off < 64; off <<= 1) {
                unsigned int o = __shfl_up(v, off, 64);
                if (lane >= off) v += o;
            }
            if (lane == 63) s_wsum[wid] = v;
            __syncthreads();                                   // B3
            unsigned int wbase = 0;
            for (int i = 0; i < wid; ++i) wbase += s_wsum[i];
            unsigned int incl = v + wbase;
            unsigned int excl = incl - cnt1;
            if (excl < capu && capu <= incl) { s_binE = (unsigned int)tid; s_belowE = excl; }
        }
        __syncthreads();                                       // B4
        const unsigned int E = s_binE;
        const unsigned int rem1 = capu - s_belowE;

        // ---------- pass 2: mantissa hist of boundary-exponent elements ----------
        #pragma unroll
        for (int c = 0; c < EPT; ++c) {
            if ((ub[c] >> 23) == E) {
                unsigned int m = (ub[c] >> 11) & 0xFFFu;
                atomicAdd(&s_h2[H2PAD(m)], 1u);
            }
        }
        __syncthreads();                                       // B5

        // ---------- rank 2: 4096 mantissa bins, 8 per thread (padded reads) ----------
        {
            const int base = tid * 8;
            unsigned int hv[8];
            unsigned int cnt8 = 0;
            #pragma unroll
            for (int j = 0; j < 8; ++j) { hv[j] = s_h2[H2PAD(base + j)]; cnt8 += hv[j]; }
            unsigned int v = cnt8;
            #pragma unroll
            for (int off = 1; off < 64; off <<= 1) {
                unsigned int o = __shfl_up(v, off, 64);
                if (lane >= off) v += o;
            }
            if (lane == 63) s_wsum[wid] = v;
            __syncthreads();                                   // B6
            unsigned int wbase = 0;
            for (int i = 0; i < wid; ++i) wbase += s_wsum[i];
            unsigned int incl = v + wbase;
            unsigned int excl = incl - cnt8;
            if (excl < rem1 && rem1 <= incl) {
                unsigned int run = excl;
                #pragma unroll
                for (int j = 0; j < 8; ++j) {
                    unsigned int c2 = hv[j];
                    if (rem1 <= run + c2) { s_binM = (unsigned int)(base + j); s_belowM = run; break; }
                    run += c2;
                }
            }
        }
        __syncthreads();                                       // B7
        const unsigned int EM   = (E << 12) | s_binM;
        const unsigned int rem2 = rem1 - s_belowM;

        // ---------- pass 3: exact tie-break among the (E,M) bin (tiny C2) ----------
        #pragma unroll
        for (int c = 0; c < EPT; ++c) {
            bool isc = ((ub[c] >> 11) == EM);
            unsigned long long m = __ballot(isc);
            if (m) {
                int leader = __builtin_ctzll(m);
                unsigned int base2 = 0;
                if (lane == leader) base2 = atomicAdd(&s_c2cnt, (unsigned int)__popcll(m));
                base2 = __shfl(base2, leader, 64);
                if (isc) {
                    unsigned int p0 = base2 + lanes_below(m);
                    if (p0 < CAND2MAX)
                        s_cand2[p0] = ((ub[c] & 0x7FFu) << 12) | (unsigned int)(c * NTH + tid);
                }
            }
        }
        __syncthreads();                                       // B8
        const int C2 = (int)min(s_c2cnt, (unsigned int)CAND2MAX);
        for (int i = tid; i < C2; i += NTH) {
            unsigned int pv = s_cand2[i];
            int less = 0;
            for (int j = 0; j < C2; ++j) less += (s_cand2[j] < pv) ? 1 : 0;
            if (less == (int)rem2 - 1) s_P = pv;   // rem2-th smallest (key,idx)
        }
        __syncthreads();                                       // B9
        const unsigned int P = s_P;

        selmask = 0;
        #pragma unroll
        for (int c = 0; c < EPT; ++c) {
            const unsigned int pre = ub[c] >> 11;
            const unsigned int key = ((ub[c] & 0x7FFu) << 12) | (unsigned int)(c * NTH + tid);
            bool s = (pre < EM) || (pre == EM && key <= P);
            selmask |= (s ? 1u : 0u) << c;
        }
    }

    // ---------- register masked accumulate (no compaction, no LDS round trip) ----------
    float accZ = 0.f, accS = 0.f;
    #pragma unroll
    for (int c = 0; c < EPT; ++c) {
        if ((selmask >> c) & 1u) {
            accZ += eN[c];
            accS += eN[c] * lp[c];
        }
    }

    // ---------- block reduction ----------
    #pragma unroll
    for (int off = 32; off; off >>= 1) {
        accZ += __shfl_down(accZ, off, 64);
        accS += __shfl_down(accS, off, 64);
    }
    if (lane == 0) { s_red[wid] = accZ; s_red[NWAVES + wid] = accS; }
    __syncthreads();                                           // B10
    if (tid == 0) {
        float Z = 0.f, S = 0.f;
        for (int i = 0; i < NWAVES; ++i) { Z += s_red[i]; S += s_red[NWAVES + i]; }
        rowres[row] = S / Z;
    }
}

__global__ void mdn_finalize_kernel(const float* __restrict__ rowres,
                                    float* __restrict__ out)
{
    int b = threadIdx.x;
    if (b < BS) {
        float s = 0.f;
        #pragma unroll
        for (int w = 0; w < NW; ++w) s += rowres[b * NW + w];
        out[b] = -s * (1.0f / NW);
    }
}

extern "C" void kernel_launch(void* const* d_in, const int* in_sizes, int n_in,
                              void* d_out, int out_size, void* d_ws, size_t ws_size,
                              hipStream_t stream)
{
    const float* mu    = (const float*)d_in[0];
    const float* sigma = (const float*)d_in[1];
    const float* pi    = (const float*)d_in[2];
    const float* neg   = (const float*)d_in[3];
    const float* pos   = (const float*)d_in[4];
    const int*   wh    = (const int*)d_in[5];
    const int*   cap   = (const int*)d_in[6];
    float* rowres = (float*)d_ws;   // BS*NW floats scratch
    float* out    = (float*)d_out;

    mdn_row_kernel<<<BS * NW, NTH, 0, stream>>>(mu, sigma, pi, neg, pos, wh, cap, rowres);
    mdn_finalize_kernel<<<1, 64, 0, stream>>>(rowres, out);
}

// Round 9
// 22.709 us; speedup vs baseline: 1.4146x; 1.1823x over previous
//
#include <hip/hip_runtime.h>
#include <math.h>

#define BS   64
#define NW   8
#define NK   10
#define NP   16
#define NT   20
#define NN   4096
#define NTH  512
#define NWAVES (NTH / 64)
#define EPT  (NN / NTH)               // 8 negatives per thread, register-resident
#define NB1  256                      // pass-1 bins: exponent byte (ub>>23), sign always 0
#define H1STR 257                     // odd copy stride -> rotated reads are bank-safe
#define NB2  4096                     // pass-2 bins: mantissa bits [22:11]
#define CAND2MAX 256
#define LOG2PI 1.8378770664093453f
#define LOG2E  1.4426950408889634f
#define LN2    0.6931471805599453f

__device__ __constant__ int d_wpix[NW] = {0, 2, 4, 6, 9, 12, 15, 19};

__device__ __forceinline__ unsigned int lanes_below(unsigned long long m) {
    unsigned int lt = __builtin_amdgcn_mbcnt_lo((unsigned int)m, 0u);
    return __builtin_amdgcn_mbcnt_hi((unsigned int)(m >> 32), lt);
}

__global__ __launch_bounds__(NTH, 4) void mdn_row_kernel(
    const float* __restrict__ mu,
    const float* __restrict__ sigma,
    const float* __restrict__ pi,
    const float* __restrict__ neg,
    const float* __restrict__ pos,
    const int* __restrict__ p_wh,
    const int* __restrict__ p_cap,
    float* __restrict__ rowres)
{
    __shared__ unsigned int s_h1[NWAVES * H1STR]; // 8KB per-wave exponent hists
    __shared__ unsigned int s_h2[NB2];            // 16KB mantissa hist; reused as sel arrays
    __shared__ unsigned int s_cand2[CAND2MAX];    // 1KB exact-tie candidates
    __shared__ float s_posx[NP], s_posy[NP];
    __shared__ float s_mu0[NK], s_mu1[NK], s_is0[NK], s_is1[NK], s_ck2[NK];
    __shared__ unsigned int s_wsum[NWAVES];
    __shared__ float s_red[2 * NWAVES];
    __shared__ unsigned int s_c2cnt;

    const int row  = blockIdx.x;      // 0 .. BS*NW-1
    const int b    = row / NW;
    const int w    = row % NW;
    const int tid  = threadIdx.x;
    const int lane = tid & 63;
    const int wid  = tid >> 6;

    // ---------- issue negative loads first (latency hides under init) ----------
    const float2* negp = (const float2*)(neg + (size_t)b * NN * 2);
    float2 nv[EPT];
    #pragma unroll
    for (int c = 0; c < EPT; ++c) nv[c] = negp[c * NTH + tid];

    // ---------- phase 0: zero hists, stage positives, mixture constants ----------
    #pragma unroll
    for (int j = 0; j < 4; ++j) {
        int i = tid + j * NTH;
        if (i < NWAVES * H1STR) s_h1[i] = 0;
    }
    #pragma unroll
    for (int j = 0; j < NB2 / NTH; ++j) s_h2[tid + j * NTH] = 0;
    if (tid < NP) {
        const float* pp = pos + (((size_t)b * NP + tid) * NT + d_wpix[w]) * 2;
        s_posx[tid] = pp[0];
        s_posy[tid] = pp[1];
    }
    if (tid >= 64 && tid < 64 + NK) {          // wave 1: per-component precompute
        const int k = tid - 64;
        const float* pib = pi    + ((size_t)b * NW + w) * NK;
        const float* mub = mu    + ((size_t)b * NW + w) * NK * 2;
        const float* sgb = sigma + ((size_t)b * NW + w) * NK * 2;
        float m = pib[0];
        for (int j = 1; j < NK; ++j) m = fmaxf(m, pib[j]);
        float se = 0.f;
        for (int j = 0; j < NK; ++j) se += __expf(pib[j] - m);
        float lse = m + __logf(se);
        float s0 = sgb[2 * k], s1 = sgb[2 * k + 1];
        s_mu0[k] = mub[2 * k];
        s_mu1[k] = mub[2 * k + 1];
        s_is0[k] = 1.0f / s0;
        s_is1[k] = 1.0f / s1;
        s_ck2[k] = ((pib[k] - lse) - __logf(s0) - __logf(s1) - LOG2PI) * LOG2E;
    }
    if (tid == 32) s_c2cnt = 0;
    __syncthreads();                                           // B1

    const int cap = *p_cap;
    const bool do_sel = (cap > 0 && cap < NN);
    const int wh = *p_wh;

    // ---------- loop A: distances + per-wave privatized exponent histogram ----------
    float px[NP], py[NP];
    #pragma unroll
    for (int p = 0; p < NP; ++p) { px[p] = s_posx[p]; py[p] = s_posy[p]; }
    unsigned int ub[EPT];
    #pragma unroll
    for (int c = 0; c < EPT; ++c) {
        float2 v = nv[c];
        float best0 = INFINITY, best1 = INFINITY;   // pairwise tree halves dep chain
        #pragma unroll
        for (int p = 0; p < NP; p += 2) {
            float dx0 = px[p] - v.x,     dy0 = py[p] - v.y;
            float dx1 = px[p + 1] - v.x, dy1 = py[p + 1] - v.y;
            best0 = fminf(best0, fmaf(dx0, dx0, dy0 * dy0));
            best1 = fminf(best1, fmaf(dx1, dx1, dy1 * dy1));
        }
        float dd = sqrtf(fminf(best0, best1));      // sqrt(min) == min(sqrt)
        ub[c] = __float_as_uint(dd);
        atomicAdd(&s_h1[wid * H1STR + (ub[c] >> 23)], 1u);
    }
    __syncthreads();                                           // B2 (h1 complete)

    unsigned int selmask = 0xFFu;
    float accZ = 0.f, accS = 0.f;

    if (do_sel) {
        const unsigned int capu = (unsigned int)cap;

        // ---------- rank 1: 256 exponent bins, 4/lane, EVERY WAVE redundantly ----------
        // (each wave sees the full bin space -> no cross-wave scan, no extra barriers)
        unsigned int binv[4] = {0u, 0u, 0u, 0u};
        {
            const int rotb = lane >> 3;
            #pragma unroll
            for (int q = 0; q < NWAVES; ++q) {
                const int cp = (q + rotb) & 7;             // rotated copy order: <=2-way banks
                #pragma unroll
                for (int j = 0; j < 4; ++j)
                    binv[j] += s_h1[cp * H1STR + lane * 4 + j];
            }
        }
        unsigned int cnt4 = binv[0] + binv[1] + binv[2] + binv[3];
        unsigned int v1 = cnt4;
        #pragma unroll
        for (int off = 1; off < 64; off <<= 1) {
            unsigned int o = __shfl_up(v1, off, 64);
            if (lane >= off) v1 += o;
        }
        const unsigned int excl1 = v1 - cnt4;
        bool hit1 = (excl1 < capu && capu <= v1);
        unsigned int binE_l = 0, belowE_l = 0;
        if (hit1) {
            unsigned int run = excl1;
            #pragma unroll
            for (int j = 0; j < 4; ++j) {
                if (capu <= run + binv[j]) { binE_l = (unsigned int)(lane * 4 + j); belowE_l = run; break; }
                run += binv[j];
            }
        }
        {
            unsigned long long hm = __ballot(hit1);
            int src = __builtin_ctzll(hm);
            binE_l  = __shfl(binE_l,  src, 64);
            belowE_l = __shfl(belowE_l, src, 64);
        }
        const unsigned int E = binE_l;
        const unsigned int rem1 = capu - belowE_l;

        // ---------- pass 2: mantissa hist of boundary-exponent elements ----------
        #pragma unroll
        for (int c = 0; c < EPT; ++c) {
            if ((ub[c] >> 23) == E)
                atomicAdd(&s_h2[(ub[c] >> 11) & 0xFFFu], 1u);
        }
        __syncthreads();                                       // B3 (h2 complete)

        // ---------- rank 2 stage A: 64-bin chunk sums (rotated reads), every wave ----------
        unsigned int csum = 0;
        {
            const int cb = lane << 6;
            #pragma unroll 8
            for (int j = 0; j < 64; ++j)
                csum += s_h2[cb + ((lane + j) & 63)];          // <=2-way banks
        }
        unsigned int v2s = csum;
        #pragma unroll
        for (int off = 1; off < 64; off <<= 1) {
            unsigned int o = __shfl_up(v2s, off, 64);
            if (lane >= off) v2s += o;
        }
        const unsigned int excl2 = v2s - csum;
        bool hit2 = (excl2 < rem1 && rem1 <= v2s);
        unsigned int chunk_l = 0, belowC_l = 0;
        if (hit2) { chunk_l = (unsigned int)lane; belowC_l = excl2; }
        {
            unsigned long long hm = __ballot(hit2);
            int src = __builtin_ctzll(hm);
            chunk_l  = __shfl(chunk_l,  src, 64);
            belowC_l = __shfl(belowC_l, src, 64);
        }
        const unsigned int remC = rem1 - belowC_l;

        // ---------- rank 2 stage B: the 64 bins of the hit chunk, one per lane ----------
        unsigned int bv = s_h2[(chunk_l << 6) + lane];
        unsigned int v3 = bv;
        #pragma unroll
        for (int off = 1; off < 64; off <<= 1) {
            unsigned int o = __shfl_up(v3, off, 64);
            if (lane >= off) v3 += o;
        }
        const unsigned int excl3 = v3 - bv;
        bool hit3 = (excl3 < remC && remC <= v3);
        unsigned int binM_l = 0, rem2_l = 0;
        if (hit3) { binM_l = (chunk_l << 6) + (unsigned int)lane; rem2_l = remC - excl3; }
        {
            unsigned long long hm = __ballot(hit3);
            int src = __builtin_ctzll(hm);
            binM_l = __shfl(binM_l, src, 64);
            rem2_l = __shfl(rem2_l, src, 64);
        }
        const unsigned int EM   = (E << 12) | binM_l;          // top-21-bit prefix of boundary
        const unsigned int rem2 = rem2_l;                      // how many to take at (E,M)

        // ---------- pass 3: exact tie-break among the (E,M) bin (tiny C2) ----------
        #pragma unroll
        for (int c = 0; c < EPT; ++c) {
            bool isc = ((ub[c] >> 11) == EM);
            unsigned long long m = __ballot(isc);
            if (m) {
                int leader = __builtin_ctzll(m);
                unsigned int base2 = 0;
                if (lane == leader) base2 = atomicAdd(&s_c2cnt, (unsigned int)__popcll(m));
                base2 = __shfl(base2, leader, 64);
                if (isc) {
                    unsigned int p0 = base2 + lanes_below(m);
                    if (p0 < CAND2MAX)
                        s_cand2[p0] = ((ub[c] & 0x7FFu) << 12) | (unsigned int)(c * NTH + tid);
                }
            }
        }
        __syncthreads();                                       // B4 (cand2 complete)

        const int C2 = (int)min(s_c2cnt, (unsigned int)CAND2MAX);
        unsigned int Pl = 0;
        bool foundP = false;
        for (int i = lane; i < C2; i += 64) {
            unsigned int pv = s_cand2[i];
            int less = 0;
            for (int j = 0; j < C2; ++j) less += (s_cand2[j] < pv) ? 1 : 0;
            if (less == (int)rem2 - 1) { foundP = true; Pl = pv; }
        }
        unsigned int P;
        {
            unsigned long long fm = __ballot(foundP);
            P = fm ? __shfl(Pl, __builtin_ctzll(fm), 64) : 0xFFFFFFFFu;
        }

        selmask = 0;
        #pragma unroll
        for (int c = 0; c < EPT; ++c) {
            const unsigned int pre = ub[c] >> 11;
            const unsigned int key = ((ub[c] & 0x7FFu) << 12) | (unsigned int)(c * NTH + tid);
            bool s = (pre < EM) || (pre == EM && key <= P);
            selmask |= (s ? 1u : 0u) << c;
        }

        // ---------- compact selected (x, y, e) into dense LDS (reuse s_h2) ----------
        int cs = __popc(selmask);
        unsigned int vsc = (unsigned int)cs;
        #pragma unroll
        for (int off = 1; off < 64; off <<= 1) {
            unsigned int o = __shfl_up(vsc, off, 64);
            if (lane >= off) vsc += o;
        }
        if (lane == 63) s_wsum[wid] = vsc;
        __syncthreads();                                       // B5 (wave totals ready)
        unsigned int wbase = 0;
        for (int i = 0; i < wid; ++i) wbase += s_wsum[i];
        int wpos = (int)(wbase + vsc - (unsigned int)cs);
        float* selx = (float*)&s_h2[0];
        float* sely = (float*)&s_h2[1024];
        float* sele = (float*)&s_h2[2048];
        #pragma unroll
        for (int c = 0; c < EPT; ++c) {
            if ((selmask >> c) & 1u) {
                float dd = __uint_as_float(ub[c]);
                selx[wpos] = wh ? nv[c].y : nv[c].x;    // reversal matters vs mu/sigma
                sely[wpos] = wh ? nv[c].x : nv[c].y;
                sele[wpos] = exp2f(-dd * LOG2E);        // exp(dmin) cancels in S/Z
                ++wpos;
            }
        }
        __syncthreads();                                       // B6 (sel arrays ready)

        // ---------- dense mixture over exactly cap selected ----------
        float cmu0[NK], cmu1[NK], cis0[NK], cis1[NK], cck2[NK];
        #pragma unroll
        for (int k = 0; k < NK; ++k) {
            cmu0[k] = s_mu0[k]; cmu1[k] = s_mu1[k];
            cis0[k] = s_is0[k]; cis1[k] = s_is1[k];
            cck2[k] = s_ck2[k];
        }
        for (int i = tid; i < cap; i += NTH) {
            const float x0 = selx[i], x1 = sely[i], e = sele[i];
            float a[NK];
            #pragma unroll
            for (int k = 0; k < NK; ++k) {
                float z0 = (x0 - cmu0[k]) * cis0[k];
                float z1 = (x1 - cmu1[k]) * cis1[k];
                float q  = fmaf(z0, z0, z1 * z1);
                a[k] = fmaf(q, -0.5f * LOG2E, cck2[k]);
            }
            float t0 = fmaxf(a[0], a[1]), t1 = fmaxf(a[2], a[3]);
            float t2 = fmaxf(a[4], a[5]), t3 = fmaxf(a[6], a[7]);
            float m2 = fmaxf(fmaxf(fmaxf(t0, t1), fmaxf(t2, t3)), fmaxf(a[8], a[9]));
            float se = 0.f;
            #pragma unroll
            for (int k = 0; k < NK; ++k) se += exp2f(a[k] - m2);
            float lp = LN2 * (m2 + log2f(se));
            accZ += e;
            accS += e * lp;
        }
    } else {
        // cold path (cap covers all): direct register mixture on owned elements
        #pragma unroll
        for (int c = 0; c < EPT; ++c) {
            const float x0 = wh ? nv[c].y : nv[c].x;
            const float x1 = wh ? nv[c].x : nv[c].y;
            const float e  = exp2f(-__uint_as_float(ub[c]) * LOG2E);
            float a[NK];
            #pragma unroll
            for (int k = 0; k < NK; ++k) {
                float z0 = (x0 - s_mu0[k]) * s_is0[k];
                float z1 = (x1 - s_mu1[k]) * s_is1[k];
                float q  = fmaf(z0, z0, z1 * z1);
                a[k] = fmaf(q, -0.5f * LOG2E, s_ck2[k]);
            }
            float t0 = fmaxf(a[0], a[1]), t1 = fmaxf(a[2], a[3]);
            float t2 = fmaxf(a[4], a[5]), t3 = fmaxf(a[6], a[7]);
            float m2 = fmaxf(fmaxf(fmaxf(t0, t1), fmaxf(t2, t3)), fmaxf(a[8], a[9]));
            float se = 0.f;
            #pragma unroll
            for (int k = 0; k < NK; ++k) se += exp2f(a[k] - m2);
            float lp = LN2 * (m2 + log2f(se));
            accZ += e;
            accS += e * lp;
        }
    }

    // ---------- block reduction ----------
    #pragma unroll
    for (int off = 32; off; off >>= 1) {
        accZ += __shfl_down(accZ, off, 64);
        accS += __shfl_down(accS, off, 64);
    }
    if (lane == 0) { s_red[wid] = accZ; s_red[NWAVES + wid] = accS; }
    __syncthreads();                                           // B7
    if (tid == 0) {
        float Z = 0.f, S = 0.f;
        for (int i = 0; i < NWAVES; ++i) { Z += s_red[i]; S += s_red[NWAVES + i]; }
        rowres[row] = S / Z;
    }
}

__global__ void mdn_finalize_kernel(const float* __restrict__ rowres,
                                    float* __restrict__ out)
{
    int b = threadIdx.x;
    if (b < BS) {
        float s = 0.f;
        #pragma unroll
        for (int w = 0; w < NW; ++w) s += rowres[b * NW + w];
        out[b] = -s * (1.0f / NW);
    }
}

extern "C" void kernel_launch(void* const* d_in, const int* in_sizes, int n_in,
                              void* d_out, int out_size, void* d_ws, size_t ws_size,
                              hipStream_t stream)
{
    const float* mu    = (const float*)d_in[0];
    const float* sigma = (const float*)d_in[1];
    const float* pi    = (const float*)d_in[2];
    const float* neg   = (const float*)d_in[3];
    const float* pos   = (const float*)d_in[4];
    const int*   wh    = (const int*)d_in[5];
    const int*   cap   = (const int*)d_in[6];
    float* rowres = (float*)d_ws;   // BS*NW floats scratch
    float* out    = (float*)d_out;

    mdn_row_kernel<<<BS * NW, NTH, 0, stream>>>(mu, sigma, pi, neg, pos, wh, cap, rowres);
    mdn_finalize_kernel<<<1, 64, 0, stream>>>(rowres, out);
}